// Round 8
// baseline (255.506 us; speedup 1.0000x reference)
//
#include <hip/hip_runtime.h>
#include <hip/hip_bf16.h>

// ---------------------------------------------------------------------------
// Round-8 structure:
//   bin_edges_all: unchanged (round 6/7).
//   gemm_all: 8x8-register-blocked GEMM, now 128-row tiles -> 640 blocks
//     (round-7's 256-row tiles gave 320 blocks = 1.25/CU, occupancy 9.7%,
//     latency-bound at 44us). XOR bank swizzle on X tile; register prefetch
//     of next K-chunk overlapped with compute.
//   gather_mlp_obs / gather_mlp_task_pool: unchanged.
// ---------------------------------------------------------------------------

#define CAP1 2816   // stage1: mean 2048/bucket, sigma~45  -> mean+17sigma
#define CAP2 5120   // stage2: mean 4096/bucket, sigma~64  -> mean+16sigma

// ------------------------- merged dense GEMM ------------------------------
// out[M,64] = X[M,128] @ W[128,64].  128-row tiles (640 blocks); 256 thr;
// thread = 8 rows x 4 cols; K chunked by 32 with register prefetch.
__global__ __launch_bounds__(256) void gemm_all(
    const float* __restrict__ x_goal, const float* __restrict__ x_obs,
    const float* __restrict__ W, float* __restrict__ xg1,
    float* __restrict__ obs)
{
    __shared__ float Ws[32 * 64];        // K-chunk of W1 (8 KB)
    __shared__ float Xs[128 * 32];       // 128-row X K-chunk, swizzled (16 KB)
    const int tid = threadIdx.x;
    const float* X;
    float* O;
    int row0;
    if (blockIdx.x < 128) { X = x_goal; O = xg1; row0 = blockIdx.x * 128; }
    else                  { X = x_obs;  O = obs; row0 = (blockIdx.x - 128) * 128; }

    // staging map: X -> thread covers (srow + 32m, quad skb), m=0..3
    const int skb = tid & 7;
    const int srow = tid >> 3;
    // compute map: 16 col-threads x 16 row-threads; 8r x 4c each
    const int tcol = tid & 15;
    const int trow = tid >> 4;
    const int c0 = tcol * 4;
    const int r0 = trow * 8;
    const int swz = trow & 7;

    float acc[8][4];
    #pragma unroll
    for (int i = 0; i < 8; ++i)
        #pragma unroll
        for (int j = 0; j < 4; ++j) acc[i][j] = 0.f;

    float4 px[4];                        // prefetched X slices
    float4 pw[2];                        // prefetched W slices
    // prefetch chunk 0
    #pragma unroll
    for (int m = 0; m < 4; ++m)
        px[m] = *(const float4*)(X + (size_t)(row0 + srow + 32 * m) * 128 + skb * 4);
    #pragma unroll
    for (int m = 0; m < 2; ++m) {
        int i = m * 256 + tid;
        pw[m] = *(const float4*)(W + (size_t)(i >> 4) * 64 + (i & 15) * 4);
    }

    for (int kc = 0; kc < 4; ++kc) {
        const int k0n = (kc + 1) * 32;
        if (kc) __syncthreads();         // previous chunk fully consumed
        // store prefetched chunk to LDS (X bank-swizzled)
        #pragma unroll
        for (int m = 0; m < 4; ++m) {
            int row = srow + 32 * m;
            *(float4*)(Xs + row * 32 + ((skb ^ ((row >> 3) & 7)) << 2)) = px[m];
        }
        #pragma unroll
        for (int m = 0; m < 2; ++m) {
            int i = m * 256 + tid;
            *(float4*)(Ws + (i >> 4) * 64 + (i & 15) * 4) = pw[m];
        }
        __syncthreads();
        // prefetch next chunk while computing this one
        if (kc < 3) {
            #pragma unroll
            for (int m = 0; m < 4; ++m)
                px[m] = *(const float4*)(X + (size_t)(row0 + srow + 32 * m) * 128 + k0n + skb * 4);
            #pragma unroll
            for (int m = 0; m < 2; ++m) {
                int i = m * 256 + tid;
                pw[m] = *(const float4*)(W + (size_t)(k0n + (i >> 4)) * 64 + (i & 15) * 4);
            }
        }
        // compute: 8 kb-steps of 4 k each (12 ds_read_b128 per 128 FMA)
        #pragma unroll
        for (int kb = 0; kb < 8; ++kb) {
            float4 xv[8];
            #pragma unroll
            for (int i = 0; i < 8; ++i)
                xv[i] = *(const float4*)(Xs + (r0 + i) * 32 + ((kb ^ swz) << 2));
            #pragma unroll
            for (int kk = 0; kk < 4; ++kk) {
                float4 wv = *(const float4*)(Ws + (kb * 4 + kk) * 64 + c0);
                #pragma unroll
                for (int i = 0; i < 8; ++i) {
                    float xk = (kk == 0) ? xv[i].x : (kk == 1) ? xv[i].y
                             : (kk == 2) ? xv[i].z : xv[i].w;
                    acc[i][0] = fmaf(xk, wv.x, acc[i][0]);
                    acc[i][1] = fmaf(xk, wv.y, acc[i][1]);
                    acc[i][2] = fmaf(xk, wv.z, acc[i][2]);
                    acc[i][3] = fmaf(xk, wv.w, acc[i][3]);
                }
            }
        }
    }
    #pragma unroll
    for (int i = 0; i < 8; ++i) {
        float4 o;
        o.x = acc[i][0]; o.y = acc[i][1]; o.z = acc[i][2]; o.w = acc[i][3];
        *(float4*)(O + (size_t)(row0 + r0 + i) * 64 + c0) = o;
    }
}

// ------------------- merged coarse binning --------------------------------
__global__ __launch_bounds__(256) void bin_edges_all(
    const int* __restrict__ go_src, const int* __restrict__ go_dst,
    const int* __restrict__ ot_src, const int* __restrict__ ot_dst,
    int* __restrict__ gcur1, int* __restrict__ gcur2,
    int* __restrict__ pairs1, int* __restrict__ pairs2, int nblk1)
{
    __shared__ int hist[512];
    __shared__ int cur[512];
    const int tid = threadIdx.x;
    const bool s1 = (int)blockIdx.x < nblk1;
    const int* src = s1 ? go_src : ot_src;
    const int* dst = s1 ? go_dst : ot_dst;
    int* gcur  = s1 ? gcur1 : gcur2;
    int* pairs = s1 ? pairs1 : pairs2;
    const int bsh  = s1 ? 7 : 5;
    const int rowm = s1 ? 127 : 31;
    const int nb   = s1 ? 512 : 256;
    const int cap  = s1 ? CAP1 : CAP2;
    const int blk  = s1 ? blockIdx.x : blockIdx.x - nblk1;

    for (int i = tid; i < nb; i += 256) hist[i] = 0;
    __syncthreads();
    const int base = blk * 4096;
    const int4* d4 = (const int4*)(dst + base);
    const int4* s4 = (const int4*)(src + base);
    int4 dv[4];
    #pragma unroll
    for (int k = 0; k < 4; ++k) {
        dv[k] = d4[k * 256 + tid];
        atomicAdd(&hist[dv[k].x >> bsh], 1);
        atomicAdd(&hist[dv[k].y >> bsh], 1);
        atomicAdd(&hist[dv[k].z >> bsh], 1);
        atomicAdd(&hist[dv[k].w >> bsh], 1);
    }
    __syncthreads();
    for (int i = tid; i < nb; i += 256)
        cur[i] = atomicAdd(&gcur[i], hist[i]);     // reserve contiguous run
    __syncthreads();
    #pragma unroll
    for (int k = 0; k < 4; ++k) {
        int4 sv = s4[k * 256 + tid];
        int d, s, b, p;
        d = dv[k].x; s = sv.x; b = d >> bsh; p = atomicAdd(&cur[b], 1);
        if (p < cap) pairs[(size_t)b * cap + p] = ((d & rowm) << 17) | s;
        d = dv[k].y; s = sv.y; b = d >> bsh; p = atomicAdd(&cur[b], 1);
        if (p < cap) pairs[(size_t)b * cap + p] = ((d & rowm) << 17) | s;
        d = dv[k].z; s = sv.z; b = d >> bsh; p = atomicAdd(&cur[b], 1);
        if (p < cap) pairs[(size_t)b * cap + p] = ((d & rowm) << 17) | s;
        d = dv[k].w; s = sv.w; b = d >> bsh; p = atomicAdd(&cur[b], 1);
        if (p < cap) pairs[(size_t)b * cap + p] = ((d & rowm) << 17) | s;
    }
}

// ------------- stage-1 gather + fused obs MLP -----------------------------
__global__ __launch_bounds__(1024) void gather_mlp_obs(
    const int* __restrict__ pairs, const int* __restrict__ cnt,
    const float* __restrict__ xg1, const float* __restrict__ obs,
    const float* __restrict__ b1, const float* __restrict__ W2,
    const float* __restrict__ b2, float* __restrict__ x1)
{
    constexpr int ROWS = 128;
    __shared__ int ssrc[CAP1];
    __shared__ int offs[ROWS + 1];
    __shared__ int rcnt[ROWS];
    __shared__ float W2t[64 * 68];       // transposed, stride 68 (16B aligned)
    __shared__ float hb[16 * 64];
    const int tid = threadIdx.x;
    const int b = blockIdx.x;

    // load + transpose W2: W2t[c][k] = W2[k][c]
    #pragma unroll
    for (int i = tid; i < 4096; i += 1024) {
        int k = i >> 6, c = i & 63;
        W2t[c * 68 + k] = W2[i];
    }
    if (tid < ROWS) rcnt[tid] = 0;
    __syncthreads();
    int n = cnt[b];
    if (n > CAP1) n = CAP1;
    const int* bp = pairs + (size_t)b * CAP1;

    // 1) histogram, caching packed edges in registers (<=3 per thread)
    int e0 = -1, e1 = -1, e2 = -1;
    {
        int i = tid;
        if (i < n) {
            e0 = bp[i]; atomicAdd(&rcnt[e0 >> 17], 1); i += 1024;
            if (i < n) {
                e1 = bp[i]; atomicAdd(&rcnt[e1 >> 17], 1); i += 1024;
                if (i < n) { e2 = bp[i]; atomicAdd(&rcnt[e2 >> 17], 1); }
            }
        }
    }
    __syncthreads();
    // 2) wave-0 shfl scan (2 elems/lane), rcnt becomes the scatter cursor
    if (tid < 64) {
        int v0 = rcnt[2 * tid], v1 = rcnt[2 * tid + 1];
        int s = v0 + v1;
        #pragma unroll
        for (int d = 1; d < 64; d <<= 1) {
            int t = __shfl_up(s, d);
            if (tid >= d) s += t;
        }
        int ex = s - v0 - v1;
        offs[2 * tid] = ex;
        offs[2 * tid + 1] = ex + v0;
        rcnt[2 * tid] = ex;
        rcnt[2 * tid + 1] = ex + v0;
        if (tid == 63) offs[ROWS] = s;
    }
    __syncthreads();
    // 3) scatter src ids into row-sorted order (register-cached edges)
    if (e0 >= 0) { int p = atomicAdd(&rcnt[e0 >> 17], 1); ssrc[p] = e0 & 0x1FFFF; }
    if (e1 >= 0) { int p = atomicAdd(&rcnt[e1 >> 17], 1); ssrc[p] = e1 & 0x1FFFF; }
    if (e2 >= 0) { int p = atomicAdd(&rcnt[e2 >> 17], 1); ssrc[p] = e2 & 0x1FFFF; }
    __syncthreads();
    // 4) per-row register gather + fused MLP (float4 LDS matvec)
    const int wv = tid >> 6;
    const int lane = tid & 63;
    const float bb1 = b1[lane];
    const float bb2 = b2[lane];
    float* hp = hb + wv * 64;
    const float4* h4 = (const float4*)hp;
    const float4* wrow = (const float4*)(W2t + lane * 68);
    for (int r = wv; r < ROWS; r += 16) {
        int beg = offs[r], end = offs[r + 1];
        float a0 = 0.f, a1 = 0.f, a2 = 0.f, a3 = 0.f;
        int e = beg;
        for (; e + 4 <= end; e += 4) {
            int s0 = ssrc[e], s1 = ssrc[e + 1], s2 = ssrc[e + 2], s3 = ssrc[e + 3];
            a0 += xg1[(size_t)s0 * 64 + lane];
            a1 += xg1[(size_t)s1 * 64 + lane];
            a2 += xg1[(size_t)s2 * 64 + lane];
            a3 += xg1[(size_t)s3 * 64 + lane];
        }
        for (; e < end; ++e)
            a0 += xg1[(size_t)ssrc[e] * 64 + lane];
        size_t gi = (((size_t)b * ROWS) + r) * 64 + lane;
        float acc = (a0 + a1) + (a2 + a3) + obs[gi];     // += x_obs@W1 base
        hp[lane] = fmaxf(acc + bb1, 0.f);                // same-wave stage
        float a = bb2;
        #pragma unroll 8
        for (int kc = 0; kc < 16; ++kc) {
            float4 hv = h4[kc];          // wave-uniform broadcast b128
            float4 wv4 = wrow[kc];       // per-lane b128
            a = fmaf(hv.x, wv4.x, a);
            a = fmaf(hv.y, wv4.y, a);
            a = fmaf(hv.z, wv4.z, a);
            a = fmaf(hv.w, wv4.w, a);
        }
        x1[gi] = fmaxf(a, 0.f);
    }
}

// ------------- stage-2 gather + fused task MLP + pool + critic ------------
// One 1024-thread WG per bucket of 32 task rows == one graph.
__global__ __launch_bounds__(1024) void gather_mlp_task_pool(
    const int* __restrict__ pairs, const int* __restrict__ cnt,
    const float* __restrict__ x1, const float* __restrict__ x_task,
    const float* __restrict__ W3, const float* __restrict__ b3,
    const float* __restrict__ W4, const float* __restrict__ b4,
    const float* __restrict__ Wc1, const float* __restrict__ bc1,
    const float* __restrict__ Wc2, const float* __restrict__ bc2,
    float* __restrict__ out)
{
    constexpr int ROWS = 32;
    __shared__ int ssrc[CAP2];
    __shared__ int offs[ROWS + 1];
    __shared__ int rcnt[ROWS];
    __shared__ float W3t[64 * 68];
    __shared__ float hb[16 * 64];
    __shared__ float xrow[ROWS];
    const int tid = threadIdx.x;
    const int b = blockIdx.x;

    #pragma unroll
    for (int i = tid; i < 4096; i += 1024) {
        int k = i >> 6, c = i & 63;
        W3t[c * 68 + k] = W3[i];
    }
    if (tid < ROWS) rcnt[tid] = 0;
    __syncthreads();
    int n = cnt[b];
    if (n > CAP2) n = CAP2;
    const int* bp = pairs + (size_t)b * CAP2;

    // 1) histogram with register-cached packed edges (<=5 per thread)
    int e0 = -1, e1 = -1, e2 = -1, e3 = -1, e4 = -1;
    {
        int i = tid;
        if (i < n) { e0 = bp[i]; atomicAdd(&rcnt[e0 >> 17], 1); i += 1024;
        if (i < n) { e1 = bp[i]; atomicAdd(&rcnt[e1 >> 17], 1); i += 1024;
        if (i < n) { e2 = bp[i]; atomicAdd(&rcnt[e2 >> 17], 1); i += 1024;
        if (i < n) { e3 = bp[i]; atomicAdd(&rcnt[e3 >> 17], 1); i += 1024;
        if (i < n) { e4 = bp[i]; atomicAdd(&rcnt[e4 >> 17], 1); } } } } }
    }
    __syncthreads();
    // 2) wave-0 shfl scan over 32 rows
    if (tid < 32) {
        int v = rcnt[tid];
        int s = v;
        #pragma unroll
        for (int d = 1; d < 32; d <<= 1) {
            int t = __shfl_up(s, d);
            if (tid >= d) s += t;
        }
        int ex = s - v;
        offs[tid] = ex;
        rcnt[tid] = ex;
        if (tid == 31) offs[ROWS] = s;
    }
    __syncthreads();
    // 3) scatter
    if (e0 >= 0) { int p = atomicAdd(&rcnt[e0 >> 17], 1); ssrc[p] = e0 & 0x1FFFF; }
    if (e1 >= 0) { int p = atomicAdd(&rcnt[e1 >> 17], 1); ssrc[p] = e1 & 0x1FFFF; }
    if (e2 >= 0) { int p = atomicAdd(&rcnt[e2 >> 17], 1); ssrc[p] = e2 & 0x1FFFF; }
    if (e3 >= 0) { int p = atomicAdd(&rcnt[e3 >> 17], 1); ssrc[p] = e3 & 0x1FFFF; }
    if (e4 >= 0) { int p = atomicAdd(&rcnt[e4 >> 17], 1); ssrc[p] = e4 & 0x1FFFF; }
    __syncthreads();

    // 4) two rows per wave: gather 8-chain + fused task MLP -> xrow[r]
    const int wv = tid >> 6;
    const int lane = tid & 63;
    const float bb3 = b3[lane];
    const float w4l = W4[lane];
    const float b4c = b4[0];
    float* hp = hb + wv * 64;
    const float4* h4 = (const float4*)hp;
    const float4* wrow = (const float4*)(W3t + lane * 68);
    #pragma unroll
    for (int half = 0; half < 2; ++half) {
        const int r = wv + half * 16;
        const int row = b * ROWS + r;
        int beg = offs[r], end = offs[r + 1];
        float a0 = 0.f, a1 = 0.f, a2 = 0.f, a3 = 0.f;
        float a4 = 0.f, a5 = 0.f, a6 = 0.f, a7 = 0.f;
        int e = beg;
        for (; e + 8 <= end; e += 8) {
            int s0 = ssrc[e],     s1 = ssrc[e + 1], s2 = ssrc[e + 2], s3 = ssrc[e + 3];
            int s4 = ssrc[e + 4], s5 = ssrc[e + 5], s6 = ssrc[e + 6], s7 = ssrc[e + 7];
            a0 += x1[(size_t)s0 * 64 + lane];
            a1 += x1[(size_t)s1 * 64 + lane];
            a2 += x1[(size_t)s2 * 64 + lane];
            a3 += x1[(size_t)s3 * 64 + lane];
            a4 += x1[(size_t)s4 * 64 + lane];
            a5 += x1[(size_t)s5 * 64 + lane];
            a6 += x1[(size_t)s6 * 64 + lane];
            a7 += x1[(size_t)s7 * 64 + lane];
        }
        for (; e < end; ++e)
            a0 += x1[(size_t)ssrc[e] * 64 + lane];
        float t = ((a0 + a1) + (a2 + a3)) + ((a4 + a5) + (a6 + a7))
                + x_task[(size_t)row * 64 + lane];
        hp[lane] = t;                            // same-wave stage (no relu)
        float a = bb3;
        #pragma unroll 8
        for (int kc = 0; kc < 16; ++kc) {
            float4 hv = h4[kc];
            float4 wv4 = wrow[kc];
            a = fmaf(hv.x, wv4.x, a);
            a = fmaf(hv.y, wv4.y, a);
            a = fmaf(hv.z, wv4.z, a);
            a = fmaf(hv.w, wv4.w, a);
        }
        float p = fmaxf(a, 0.f) * w4l;
        p += __shfl_xor(p, 1);
        p += __shfl_xor(p, 2);
        p += __shfl_xor(p, 4);
        p += __shfl_xor(p, 8);
        p += __shfl_xor(p, 16);
        p += __shfl_xor(p, 32);
        if (lane == 0) xrow[r] = p + b4c;
    }
    __syncthreads();
    // 5) pool + critic for this graph
    if (tid == 0) {
        float mx = -1e30f, sm = 0.f;
        #pragma unroll
        for (int i = 0; i < ROWS; ++i) {
            float v = xrow[i];
            mx = fmaxf(mx, v);
            sm += v;
        }
        float mn = sm * (1.f / 32.f);
        float o = bc2[0];
        #pragma unroll
        for (int j = 0; j < 8; ++j) {
            float t = fmaxf(mx * Wc1[j] + mn * Wc1[8 + j] + bc1[j], 0.f);
            o = fmaf(t, Wc2[j], o);
        }
        out[b] = o;
    }
}

extern "C" void kernel_launch(void* const* d_in, const int* in_sizes, int n_in,
                              void* d_out, int out_size, void* d_ws, size_t ws_size,
                              hipStream_t stream)
{
    const float* x_goal = (const float*)d_in[0];
    const float* x_obs  = (const float*)d_in[1];
    const float* x_task = (const float*)d_in[2];
    const int* go_src = (const int*)d_in[3];
    const int* go_dst = (const int*)d_in[4];
    const int* ot_src = (const int*)d_in[5];
    const int* ot_dst = (const int*)d_in[6];
    const float* W1  = (const float*)d_in[8];
    const float* b1  = (const float*)d_in[9];
    const float* W2  = (const float*)d_in[10];
    const float* b2  = (const float*)d_in[11];
    const float* W3  = (const float*)d_in[12];
    const float* b3  = (const float*)d_in[13];
    const float* W4  = (const float*)d_in[14];
    const float* b4  = (const float*)d_in[15];
    const float* Wc1 = (const float*)d_in[16];
    const float* bc1 = (const float*)d_in[17];
    const float* Wc2 = (const float*)d_in[18];
    const float* bc2 = (const float*)d_in[19];
    float* out = (float*)d_out;

    const int N_GOAL = 16384, N_OBS = 65536;
    const int E1 = in_sizes[3], E2 = in_sizes[5];
    const int NB1 = 512, NB2 = 256;

    // workspace (~47 MB of 256 MiB)
    char* w = (char*)d_ws;
    float* obs    = (float*)w;  w += (size_t)N_OBS * 64 * 4;        // 16 MB
    float* x1     = (float*)w;  w += (size_t)N_OBS * 64 * 4;        // 16 MB
    float* xg1    = (float*)w;  w += (size_t)N_GOAL * 64 * 4;       //  4 MB
    int*   pairs1 = (int*)w;    w += (size_t)NB1 * CAP1 * 4;        //  5.8 MB
    int*   pairs2 = (int*)w;    w += (size_t)NB2 * CAP2 * 4;        //  5.2 MB
    int*   gcur1  = (int*)w;    w += NB1 * 4;
    int*   gcur2  = (int*)w;    w += NB2 * 4;

    hipMemsetAsync(gcur1, 0, (NB1 + NB2) * 4, stream);

    const int nblk1 = E1 / 4096;
    bin_edges_all<<<nblk1 + E2 / 4096, 256, 0, stream>>>(
        go_src, go_dst, ot_src, ot_dst, gcur1, gcur2, pairs1, pairs2, nblk1);
    gemm_all<<<(N_GOAL + N_OBS) / 128, 256, 0, stream>>>(x_goal, x_obs, W1, xg1, obs);
    gather_mlp_obs<<<NB1, 1024, 0, stream>>>(pairs1, gcur1, xg1, obs, b1, W2, b2, x1);
    gather_mlp_task_pool<<<NB2, 1024, 0, stream>>>(pairs2, gcur2, x1, x_task,
                                                   W3, b3, W4, b4,
                                                   Wc1, bc1, Wc2, bc2, out);
}

// Round 9
// 240.009 us; speedup vs baseline: 1.0646x; 1.0646x over previous
//
#include <hip/hip_runtime.h>
#include <hip/hip_bf16.h>

// ---------------------------------------------------------------------------
// Round-9 structure:
//   prep (ONE dispatch): blocks 0..319 run the round-7 256-row 8x8-register
//     GEMM (xg1 = x_goal@W1, obs = x_obs@W1); blocks 320..831 run the coarse
//     edge binning for both edge sets.  The GEMM is LDS/VALU-bound at low
//     occupancy (r7: 9.7% occ, 44us; r8 retile: 52us) while binning is
//     memory-latency-bound — co-resident heterogeneous blocks fill each
//     other's stall cycles (m114: separate pipes co-schedule at max, not
//     sum).  LDS is a 40KB union (GEMM: Ws 8K + Xs 32K; bin: 4KB hist/cur).
//   gather_mlp_obs: per bucket (128 obs rows), register-cached counting sort
//     (wave-0 shfl scan), per-row register gather, fused obs MLP with float4
//     LDS matvec.  [unchanged]
//   gather_mlp_task_pool: per bucket (= 1 graph, 32 task rows), same sort,
//     8-chain gather from x1, fused W3 matvec + W4 dot + max/mean pool +
//     critic MLP -> out[graph].  [unchanged]
// ---------------------------------------------------------------------------

#define CAP1 2816   // stage1: mean 2048/bucket, sigma~45  -> mean+17sigma
#define CAP2 5120   // stage2: mean 4096/bucket, sigma~64  -> mean+16sigma
#define GEMM_BLKS 320   // 64 goal + 256 obs (256-row tiles)

// --------------------- merged prep: GEMM + binning ------------------------
__global__ __launch_bounds__(256) void prep(
    const float* __restrict__ x_goal, const float* __restrict__ x_obs,
    const float* __restrict__ W, float* __restrict__ xg1,
    float* __restrict__ obs,
    const int* __restrict__ go_src, const int* __restrict__ go_dst,
    const int* __restrict__ ot_src, const int* __restrict__ ot_dst,
    int* __restrict__ gcur1, int* __restrict__ gcur2,
    int* __restrict__ pairs1, int* __restrict__ pairs2, int nblk1)
{
    __shared__ float smem[10240];        // 40 KB union
    const int tid = threadIdx.x;

    if (blockIdx.x < GEMM_BLKS) {
        // ---------------- round-7 8x8 register-blocked GEMM ----------------
        float* Ws = smem;                // [32*64]  8 KB
        float* Xs = smem + 32 * 64;      // [256*32] 32 KB (swizzled)
        const float* X;
        float* O;
        int row0;
        if (blockIdx.x < 64) { X = x_goal; O = xg1; row0 = blockIdx.x * 256; }
        else                 { X = x_obs;  O = obs; row0 = (blockIdx.x - 64) * 256; }
        const int c0 = (tid & 7) * 8;
        const int trow = tid >> 3;
        const int r0 = trow * 8;
        const int swz = trow & 7;
        float acc[8][8];
        #pragma unroll
        for (int i = 0; i < 8; ++i)
            #pragma unroll
            for (int j = 0; j < 8; ++j) acc[i][j] = 0.f;

        for (int kc = 0; kc < 4; ++kc) {
            const int k0 = kc * 32;
            if (kc) __syncthreads();
            #pragma unroll
            for (int m = 0; m < 2; ++m) {
                int i = m * 256 + tid;
                int k = i >> 4, c4 = i & 15;
                *(float4*)(Ws + k * 64 + c4 * 4) =
                    *(const float4*)(W + (size_t)(k0 + k) * 64 + c4 * 4);
            }
            #pragma unroll
            for (int m = 0; m < 8; ++m) {
                int kb = tid & 7;
                int tr = tid >> 3;
                int row = tr * 8 + m;
                float4 v = *(const float4*)(X + (size_t)(row0 + row) * 128 + k0 + kb * 4);
                *(float4*)(Xs + row * 32 + ((kb ^ (tr & 7)) << 2)) = v;
            }
            __syncthreads();
            #pragma unroll 2
            for (int kb = 0; kb < 8; ++kb) {
                float4 xv[8];
                #pragma unroll
                for (int i = 0; i < 8; ++i)
                    xv[i] = *(const float4*)(Xs + (r0 + i) * 32 + ((kb ^ swz) << 2));
                #pragma unroll
                for (int kk = 0; kk < 4; ++kk) {
                    float4 w0 = *(const float4*)(Ws + (kb * 4 + kk) * 64 + c0);
                    float4 w1 = *(const float4*)(Ws + (kb * 4 + kk) * 64 + c0 + 4);
                    #pragma unroll
                    for (int i = 0; i < 8; ++i) {
                        float xk = (kk == 0) ? xv[i].x : (kk == 1) ? xv[i].y
                                 : (kk == 2) ? xv[i].z : xv[i].w;
                        acc[i][0] = fmaf(xk, w0.x, acc[i][0]);
                        acc[i][1] = fmaf(xk, w0.y, acc[i][1]);
                        acc[i][2] = fmaf(xk, w0.z, acc[i][2]);
                        acc[i][3] = fmaf(xk, w0.w, acc[i][3]);
                        acc[i][4] = fmaf(xk, w1.x, acc[i][4]);
                        acc[i][5] = fmaf(xk, w1.y, acc[i][5]);
                        acc[i][6] = fmaf(xk, w1.z, acc[i][6]);
                        acc[i][7] = fmaf(xk, w1.w, acc[i][7]);
                    }
                }
            }
        }
        #pragma unroll
        for (int i = 0; i < 8; ++i) {
            float4 o0; o0.x = acc[i][0]; o0.y = acc[i][1]; o0.z = acc[i][2]; o0.w = acc[i][3];
            float4 o1; o1.x = acc[i][4]; o1.y = acc[i][5]; o1.z = acc[i][6]; o1.w = acc[i][7];
            float* p = O + (size_t)(row0 + r0 + i) * 64 + c0;
            *(float4*)p = o0;
            *(float4*)(p + 4) = o1;
        }
    } else {
        // ----------------------- coarse binning ----------------------------
        int* hist = (int*)smem;          // [512]
        int* cur  = (int*)smem + 512;    // [512]
        const int blk2 = blockIdx.x - GEMM_BLKS;
        const bool s1 = blk2 < nblk1;
        const int* src = s1 ? go_src : ot_src;
        const int* dst = s1 ? go_dst : ot_dst;
        int* gcur  = s1 ? gcur1 : gcur2;
        int* pairs = s1 ? pairs1 : pairs2;
        const int bsh  = s1 ? 7 : 5;
        const int rowm = s1 ? 127 : 31;
        const int nb   = s1 ? 512 : 256;
        const int cap  = s1 ? CAP1 : CAP2;
        const int blk  = s1 ? blk2 : blk2 - nblk1;

        for (int i = tid; i < nb; i += 256) hist[i] = 0;
        __syncthreads();
        const int base = blk * 4096;
        const int4* d4 = (const int4*)(dst + base);
        const int4* s4 = (const int4*)(src + base);
        int4 dv[4];
        #pragma unroll
        for (int k = 0; k < 4; ++k) {
            dv[k] = d4[k * 256 + tid];
            atomicAdd(&hist[dv[k].x >> bsh], 1);
            atomicAdd(&hist[dv[k].y >> bsh], 1);
            atomicAdd(&hist[dv[k].z >> bsh], 1);
            atomicAdd(&hist[dv[k].w >> bsh], 1);
        }
        __syncthreads();
        for (int i = tid; i < nb; i += 256)
            cur[i] = atomicAdd(&gcur[i], hist[i]);   // reserve contiguous run
        __syncthreads();
        #pragma unroll
        for (int k = 0; k < 4; ++k) {
            int4 sv = s4[k * 256 + tid];
            int d, s, b, p;
            d = dv[k].x; s = sv.x; b = d >> bsh; p = atomicAdd(&cur[b], 1);
            if (p < cap) pairs[(size_t)b * cap + p] = ((d & rowm) << 17) | s;
            d = dv[k].y; s = sv.y; b = d >> bsh; p = atomicAdd(&cur[b], 1);
            if (p < cap) pairs[(size_t)b * cap + p] = ((d & rowm) << 17) | s;
            d = dv[k].z; s = sv.z; b = d >> bsh; p = atomicAdd(&cur[b], 1);
            if (p < cap) pairs[(size_t)b * cap + p] = ((d & rowm) << 17) | s;
            d = dv[k].w; s = sv.w; b = d >> bsh; p = atomicAdd(&cur[b], 1);
            if (p < cap) pairs[(size_t)b * cap + p] = ((d & rowm) << 17) | s;
        }
    }
}

// ------------- stage-1 gather + fused obs MLP -----------------------------
__global__ __launch_bounds__(1024) void gather_mlp_obs(
    const int* __restrict__ pairs, const int* __restrict__ cnt,
    const float* __restrict__ xg1, const float* __restrict__ obs,
    const float* __restrict__ b1, const float* __restrict__ W2,
    const float* __restrict__ b2, float* __restrict__ x1)
{
    constexpr int ROWS = 128;
    __shared__ int ssrc[CAP1];
    __shared__ int offs[ROWS + 1];
    __shared__ int rcnt[ROWS];
    __shared__ float W2t[64 * 68];       // transposed, stride 68 (16B aligned)
    __shared__ float hb[16 * 64];
    const int tid = threadIdx.x;
    const int b = blockIdx.x;

    // load + transpose W2: W2t[c][k] = W2[k][c]
    #pragma unroll
    for (int i = tid; i < 4096; i += 1024) {
        int k = i >> 6, c = i & 63;
        W2t[c * 68 + k] = W2[i];
    }
    if (tid < ROWS) rcnt[tid] = 0;
    __syncthreads();
    int n = cnt[b];
    if (n > CAP1) n = CAP1;
    const int* bp = pairs + (size_t)b * CAP1;

    // 1) histogram, caching packed edges in registers (<=3 per thread)
    int e0 = -1, e1 = -1, e2 = -1;
    {
        int i = tid;
        if (i < n) {
            e0 = bp[i]; atomicAdd(&rcnt[e0 >> 17], 1); i += 1024;
            if (i < n) {
                e1 = bp[i]; atomicAdd(&rcnt[e1 >> 17], 1); i += 1024;
                if (i < n) { e2 = bp[i]; atomicAdd(&rcnt[e2 >> 17], 1); }
            }
        }
    }
    __syncthreads();
    // 2) wave-0 shfl scan (2 elems/lane), rcnt becomes the scatter cursor
    if (tid < 64) {
        int v0 = rcnt[2 * tid], v1 = rcnt[2 * tid + 1];
        int s = v0 + v1;
        #pragma unroll
        for (int d = 1; d < 64; d <<= 1) {
            int t = __shfl_up(s, d);
            if (tid >= d) s += t;
        }
        int ex = s - v0 - v1;
        offs[2 * tid] = ex;
        offs[2 * tid + 1] = ex + v0;
        rcnt[2 * tid] = ex;
        rcnt[2 * tid + 1] = ex + v0;
        if (tid == 63) offs[ROWS] = s;
    }
    __syncthreads();
    // 3) scatter src ids into row-sorted order (register-cached edges)
    if (e0 >= 0) { int p = atomicAdd(&rcnt[e0 >> 17], 1); ssrc[p] = e0 & 0x1FFFF; }
    if (e1 >= 0) { int p = atomicAdd(&rcnt[e1 >> 17], 1); ssrc[p] = e1 & 0x1FFFF; }
    if (e2 >= 0) { int p = atomicAdd(&rcnt[e2 >> 17], 1); ssrc[p] = e2 & 0x1FFFF; }
    __syncthreads();
    // 4) per-row register gather + fused MLP (float4 LDS matvec)
    const int wv = tid >> 6;
    const int lane = tid & 63;
    const float bb1 = b1[lane];
    const float bb2 = b2[lane];
    float* hp = hb + wv * 64;
    const float4* h4 = (const float4*)hp;
    const float4* wrow = (const float4*)(W2t + lane * 68);
    for (int r = wv; r < ROWS; r += 16) {
        int beg = offs[r], end = offs[r + 1];
        float a0 = 0.f, a1 = 0.f, a2 = 0.f, a3 = 0.f;
        int e = beg;
        for (; e + 4 <= end; e += 4) {
            int s0 = ssrc[e], s1 = ssrc[e + 1], s2 = ssrc[e + 2], s3 = ssrc[e + 3];
            a0 += xg1[(size_t)s0 * 64 + lane];
            a1 += xg1[(size_t)s1 * 64 + lane];
            a2 += xg1[(size_t)s2 * 64 + lane];
            a3 += xg1[(size_t)s3 * 64 + lane];
        }
        for (; e < end; ++e)
            a0 += xg1[(size_t)ssrc[e] * 64 + lane];
        size_t gi = (((size_t)b * ROWS) + r) * 64 + lane;
        float acc = (a0 + a1) + (a2 + a3) + obs[gi];     // += x_obs@W1 base
        hp[lane] = fmaxf(acc + bb1, 0.f);                // same-wave stage
        float a = bb2;
        #pragma unroll 8
        for (int kc = 0; kc < 16; ++kc) {
            float4 hv = h4[kc];          // wave-uniform broadcast b128
            float4 wv4 = wrow[kc];       // per-lane b128
            a = fmaf(hv.x, wv4.x, a);
            a = fmaf(hv.y, wv4.y, a);
            a = fmaf(hv.z, wv4.z, a);
            a = fmaf(hv.w, wv4.w, a);
        }
        x1[gi] = fmaxf(a, 0.f);
    }
}

// ------------- stage-2 gather + fused task MLP + pool + critic ------------
// One 1024-thread WG per bucket of 32 task rows == one graph.
__global__ __launch_bounds__(1024) void gather_mlp_task_pool(
    const int* __restrict__ pairs, const int* __restrict__ cnt,
    const float* __restrict__ x1, const float* __restrict__ x_task,
    const float* __restrict__ W3, const float* __restrict__ b3,
    const float* __restrict__ W4, const float* __restrict__ b4,
    const float* __restrict__ Wc1, const float* __restrict__ bc1,
    const float* __restrict__ Wc2, const float* __restrict__ bc2,
    float* __restrict__ out)
{
    constexpr int ROWS = 32;
    __shared__ int ssrc[CAP2];
    __shared__ int offs[ROWS + 1];
    __shared__ int rcnt[ROWS];
    __shared__ float W3t[64 * 68];
    __shared__ float hb[16 * 64];
    __shared__ float xrow[ROWS];
    const int tid = threadIdx.x;
    const int b = blockIdx.x;

    #pragma unroll
    for (int i = tid; i < 4096; i += 1024) {
        int k = i >> 6, c = i & 63;
        W3t[c * 68 + k] = W3[i];
    }
    if (tid < ROWS) rcnt[tid] = 0;
    __syncthreads();
    int n = cnt[b];
    if (n > CAP2) n = CAP2;
    const int* bp = pairs + (size_t)b * CAP2;

    // 1) histogram with register-cached packed edges (<=5 per thread)
    int e0 = -1, e1 = -1, e2 = -1, e3 = -1, e4 = -1;
    {
        int i = tid;
        if (i < n) { e0 = bp[i]; atomicAdd(&rcnt[e0 >> 17], 1); i += 1024;
        if (i < n) { e1 = bp[i]; atomicAdd(&rcnt[e1 >> 17], 1); i += 1024;
        if (i < n) { e2 = bp[i]; atomicAdd(&rcnt[e2 >> 17], 1); i += 1024;
        if (i < n) { e3 = bp[i]; atomicAdd(&rcnt[e3 >> 17], 1); i += 1024;
        if (i < n) { e4 = bp[i]; atomicAdd(&rcnt[e4 >> 17], 1); } } } } }
    }
    __syncthreads();
    // 2) wave-0 shfl scan over 32 rows
    if (tid < 32) {
        int v = rcnt[tid];
        int s = v;
        #pragma unroll
        for (int d = 1; d < 32; d <<= 1) {
            int t = __shfl_up(s, d);
            if (tid >= d) s += t;
        }
        int ex = s - v;
        offs[tid] = ex;
        rcnt[tid] = ex;
        if (tid == 31) offs[ROWS] = s;
    }
    __syncthreads();
    // 3) scatter
    if (e0 >= 0) { int p = atomicAdd(&rcnt[e0 >> 17], 1); ssrc[p] = e0 & 0x1FFFF; }
    if (e1 >= 0) { int p = atomicAdd(&rcnt[e1 >> 17], 1); ssrc[p] = e1 & 0x1FFFF; }
    if (e2 >= 0) { int p = atomicAdd(&rcnt[e2 >> 17], 1); ssrc[p] = e2 & 0x1FFFF; }
    if (e3 >= 0) { int p = atomicAdd(&rcnt[e3 >> 17], 1); ssrc[p] = e3 & 0x1FFFF; }
    if (e4 >= 0) { int p = atomicAdd(&rcnt[e4 >> 17], 1); ssrc[p] = e4 & 0x1FFFF; }
    __syncthreads();

    // 4) two rows per wave: gather 8-chain + fused task MLP -> xrow[r]
    const int wv = tid >> 6;
    const int lane = tid & 63;
    const float bb3 = b3[lane];
    const float w4l = W4[lane];
    const float b4c = b4[0];
    float* hp = hb + wv * 64;
    const float4* h4 = (const float4*)hp;
    const float4* wrow = (const float4*)(W3t + lane * 68);
    #pragma unroll
    for (int half = 0; half < 2; ++half) {
        const int r = wv + half * 16;
        const int row = b * ROWS + r;
        int beg = offs[r], end = offs[r + 1];
        float a0 = 0.f, a1 = 0.f, a2 = 0.f, a3 = 0.f;
        float a4 = 0.f, a5 = 0.f, a6 = 0.f, a7 = 0.f;
        int e = beg;
        for (; e + 8 <= end; e += 8) {
            int s0 = ssrc[e],     s1 = ssrc[e + 1], s2 = ssrc[e + 2], s3 = ssrc[e + 3];
            int s4 = ssrc[e + 4], s5 = ssrc[e + 5], s6 = ssrc[e + 6], s7 = ssrc[e + 7];
            a0 += x1[(size_t)s0 * 64 + lane];
            a1 += x1[(size_t)s1 * 64 + lane];
            a2 += x1[(size_t)s2 * 64 + lane];
            a3 += x1[(size_t)s3 * 64 + lane];
            a4 += x1[(size_t)s4 * 64 + lane];
            a5 += x1[(size_t)s5 * 64 + lane];
            a6 += x1[(size_t)s6 * 64 + lane];
            a7 += x1[(size_t)s7 * 64 + lane];
        }
        for (; e < end; ++e)
            a0 += x1[(size_t)ssrc[e] * 64 + lane];
        float t = ((a0 + a1) + (a2 + a3)) + ((a4 + a5) + (a6 + a7))
                + x_task[(size_t)row * 64 + lane];
        hp[lane] = t;                            // same-wave stage (no relu)
        float a = bb3;
        #pragma unroll 8
        for (int kc = 0; kc < 16; ++kc) {
            float4 hv = h4[kc];
            float4 wv4 = wrow[kc];
            a = fmaf(hv.x, wv4.x, a);
            a = fmaf(hv.y, wv4.y, a);
            a = fmaf(hv.z, wv4.z, a);
            a = fmaf(hv.w, wv4.w, a);
        }
        float p = fmaxf(a, 0.f) * w4l;
        p += __shfl_xor(p, 1);
        p += __shfl_xor(p, 2);
        p += __shfl_xor(p, 4);
        p += __shfl_xor(p, 8);
        p += __shfl_xor(p, 16);
        p += __shfl_xor(p, 32);
        if (lane == 0) xrow[r] = p + b4c;
    }
    __syncthreads();
    // 5) pool + critic for this graph
    if (tid == 0) {
        float mx = -1e30f, sm = 0.f;
        #pragma unroll
        for (int i = 0; i < ROWS; ++i) {
            float v = xrow[i];
            mx = fmaxf(mx, v);
            sm += v;
        }
        float mn = sm * (1.f / 32.f);
        float o = bc2[0];
        #pragma unroll
        for (int j = 0; j < 8; ++j) {
            float t = fmaxf(mx * Wc1[j] + mn * Wc1[8 + j] + bc1[j], 0.f);
            o = fmaf(t, Wc2[j], o);
        }
        out[b] = o;
    }
}

extern "C" void kernel_launch(void* const* d_in, const int* in_sizes, int n_in,
                              void* d_out, int out_size, void* d_ws, size_t ws_size,
                              hipStream_t stream)
{
    const float* x_goal = (const float*)d_in[0];
    const float* x_obs  = (const float*)d_in[1];
    const float* x_task = (const float*)d_in[2];
    const int* go_src = (const int*)d_in[3];
    const int* go_dst = (const int*)d_in[4];
    const int* ot_src = (const int*)d_in[5];
    const int* ot_dst = (const int*)d_in[6];
    const float* W1  = (const float*)d_in[8];
    const float* b1  = (const float*)d_in[9];
    const float* W2  = (const float*)d_in[10];
    const float* b2  = (const float*)d_in[11];
    const float* W3  = (const float*)d_in[12];
    const float* b3  = (const float*)d_in[13];
    const float* W4  = (const float*)d_in[14];
    const float* b4  = (const float*)d_in[15];
    const float* Wc1 = (const float*)d_in[16];
    const float* bc1 = (const float*)d_in[17];
    const float* Wc2 = (const float*)d_in[18];
    const float* bc2 = (const float*)d_in[19];
    float* out = (float*)d_out;

    const int N_OBS = 65536, N_GOAL = 16384;
    const int E1 = in_sizes[3], E2 = in_sizes[5];
    const int NB1 = 512, NB2 = 256;

    // workspace (~47 MB of 256 MiB)
    char* w = (char*)d_ws;
    float* obs    = (float*)w;  w += (size_t)N_OBS * 64 * 4;        // 16 MB
    float* x1     = (float*)w;  w += (size_t)N_OBS * 64 * 4;        // 16 MB
    float* xg1    = (float*)w;  w += (size_t)N_GOAL * 64 * 4;       //  4 MB
    int*   pairs1 = (int*)w;    w += (size_t)NB1 * CAP1 * 4;        //  5.8 MB
    int*   pairs2 = (int*)w;    w += (size_t)NB2 * CAP2 * 4;        //  5.2 MB
    int*   gcur1  = (int*)w;    w += NB1 * 4;
    int*   gcur2  = (int*)w;    w += NB2 * 4;

    hipMemsetAsync(gcur1, 0, (NB1 + NB2) * 4, stream);

    const int nblk1 = E1 / 4096;
    const int nblk2 = E2 / 4096;
    prep<<<GEMM_BLKS + nblk1 + nblk2, 256, 0, stream>>>(
        x_goal, x_obs, W1, xg1, obs,
        go_src, go_dst, ot_src, ot_dst, gcur1, gcur2, pairs1, pairs2, nblk1);
    gather_mlp_obs<<<NB1, 1024, 0, stream>>>(pairs1, gcur1, xg1, obs, b1, W2, b2, x1);
    gather_mlp_task_pool<<<NB2, 1024, 0, stream>>>(pairs2, gcur2, x1, x_task,
                                                   W3, b3, W4, b4,
                                                   Wc1, bc1, Wc2, bc2, out);
}